// Round 5
// baseline (308.273 us; speedup 1.0000x reference)
//
#include <hip/hip_runtime.h>
#include <math.h>

#define NC 4096
#define OVCAP 131072

// ============================ FAST PATH ==========================================
// k_scatter: bin voxels into per-(cluster,shard) contiguous float4 bins (1 global
// counter atomic + ONE aligned 16B store per voxel). Streaming reads are
// NON-TEMPORAL so they don't evict partially-filled scatter lines from L2.
// k_reduce: block-per-cluster atomic-free moment reduction + inline eigensolve.
// k_sc:     block-per-cluster sc reduction (+ overflow list) + v0 finalize.

__global__ __launch_bounds__(256) void k_scatter(const float* __restrict__ data,
                                                 const int* __restrict__ ids,
                                                 float4* __restrict__ P,
                                                 int* __restrict__ cnt,
                                                 float4* __restrict__ ov,
                                                 int* __restrict__ novf,
                                                 float* __restrict__ gmom,
                                                 int n, int NSH, int CAP) {
    __shared__ float st[256 * 5];
    int shard = blockIdx.x & (NSH - 1);   // ~XCD id under round-robin dispatch
    int ntiles = (n + 255) / 256;
    for (int t = blockIdx.x; t < ntiles; t += gridDim.x) {
        int vbase = t * 256;
        int fbase = vbase * 5;
        int nf = min(256 * 5, n * 5 - fbase);
        for (int j = threadIdx.x; j < nf; j += 256)
            st[j] = __builtin_nontemporal_load(&data[fbase + j]);
        __syncthreads();
        int v = vbase + threadIdx.x;
        if (v < n) {
            int l = threadIdx.x * 5;
            float x = st[l], y = st[l + 1], z = st[l + 2];
            int id = __builtin_nontemporal_load(&ids[v]);
            int sub = id * NSH + shard;
            int pos = atomicAdd(&cnt[sub], 1);
            if (pos < CAP) {
                P[(size_t)sub * CAP + pos] = make_float4(x, y, z, 0.0f);
            } else {
                // rare overflow: moments exactly via global atomics; sc via list
                int ovi = atomicAdd(novf, 1);
                if (ovi < OVCAP) ov[ovi] = make_float4(x, y, z, __int_as_float(id));
                atomicAdd(&gmom[0 * NC + id], 1.0f);
                atomicAdd(&gmom[1 * NC + id], x);
                atomicAdd(&gmom[2 * NC + id], y);
                atomicAdd(&gmom[3 * NC + id], z);
                atomicAdd(&gmom[4 * NC + id], x * x);
                atomicAdd(&gmom[5 * NC + id], x * y);
                atomicAdd(&gmom[6 * NC + id], x * z);
                atomicAdd(&gmom[7 * NC + id], y * y);
                atomicAdd(&gmom[8 * NC + id], y * z);
                atomicAdd(&gmom[9 * NC + id], z * z);
            }
        }
        __syncthreads();
    }
}

// ---------------- k_reduce: moments + eigensolve + B/center/count ---------------
// pc[c] = {cx, cy, cz, dirwt}; pv[c] = {vx, vy, vz, cnt}
__global__ __launch_bounds__(256) void k_reduce(const float4* __restrict__ P,
                                                const int* __restrict__ cnt,
                                                const float* __restrict__ gmom,
                                                float* __restrict__ out,
                                                float4* __restrict__ pc,
                                                float4* __restrict__ pv,
                                                int NSH, int CAP) {
    __shared__ float red[4 * 10];
    __shared__ float mom[10];
    int c = blockIdx.x;
    int tid = threadIdx.x;
    float a0 = 0, a1 = 0, a2 = 0, a3 = 0, a4 = 0, a5 = 0, a6 = 0, a7 = 0, a8 = 0, a9 = 0;
    for (int s = 0; s < NSH; s++) {
        int sub = c * NSH + s;
        int m = min(cnt[sub], CAP);
        size_t base = (size_t)sub * CAP;
        for (int i = tid; i < m; i += 256) {
            float4 d = P[base + i];
            float x = d.x, y = d.y, z = d.z;
            a0 += 1.0f;
            a1 += x; a2 += y; a3 += z;
            a4 += x * x; a5 += x * y; a6 += x * z;
            a7 += y * y; a8 += y * z; a9 += z * z;
        }
    }
    float acc[10] = {a0, a1, a2, a3, a4, a5, a6, a7, a8, a9};
    int wid = tid >> 6, lane = tid & 63;
#pragma unroll
    for (int k = 0; k < 10; k++) {
        float v = acc[k];
        for (int off = 32; off > 0; off >>= 1) v += __shfl_down(v, off);
        if (lane == 0) red[wid * 10 + k] = v;
    }
    __syncthreads();
    if (tid < 10) {
        // overflow contributions were pre-added into gmom by k_scatter
        mom[tid] = red[0 + tid] + red[10 + tid] + red[20 + tid] + red[30 + tid]
                 + gmom[tid * NC + c];
    }
    __syncthreads();
    if (tid != 0) return;

    float cntf = mom[0];
    double dn  = (double)cntf;
    double inv = 1.0 / fmax(dn, 1.0);
    double cx = mom[1] * inv, cy = mom[2] * inv, cz = mom[3] * inv;

    double a00 = (double)mom[4] - dn * cx * cx;
    double a01 = (double)mom[5] - dn * cx * cy;
    double a02 = (double)mom[6] - dn * cx * cz;
    double a11 = (double)mom[7] - dn * cy * cy;
    double a12 = (double)mom[8] - dn * cy * cz;
    double a22 = (double)mom[9] - dn * cz * cz;

    // Smith's trigonometric eigenvalues
    double q  = (a00 + a11 + a22) / 3.0;
    double p1 = a01 * a01 + a02 * a02 + a12 * a12;
    double b00 = a00 - q, b11 = a11 - q, b22 = a22 - q;
    double p2 = b00 * b00 + b11 * b11 + b22 * b22 + 2.0 * p1;
    double w0, w1, w2;
    if (!(p2 > 0.0)) {
        w0 = w1 = w2 = q;
    } else {
        double p  = sqrt(p2 / 6.0);
        double ip = 1.0 / p;
        double c00 = b00 * ip, c01 = a01 * ip, c02 = a02 * ip;
        double c11 = b11 * ip, c12 = a12 * ip, c22 = b22 * ip;
        double detB = c00 * (c11 * c22 - c12 * c12)
                    - c01 * (c01 * c22 - c12 * c02)
                    + c02 * (c01 * c12 - c11 * c02);
        double r = fmin(1.0, fmax(-1.0, detB * 0.5));
        double phi = acos(r) / 3.0;
        w2 = q + 2.0 * p * cos(phi);
        w0 = q + 2.0 * p * cos(phi + 2.0943951023931953);
        w1 = 3.0 * q - w2 - w0;
    }

    double denom = (w2 == 0.0) ? 1.0 : w2;
    double dirwt = (w2 == 0.0) ? 0.0 : (1.0 - w1 / w2);

    // eigenvector of w2 via (A - w1 I)(A - w0 I)
    double C00 = a00 - w1, C11 = a11 - w1, C22 = a22 - w1;
    double D00 = a00 - w0, D11 = a11 - w0, D22 = a22 - w0;
    double M00 = C00 * D00 + a01 * a01 + a02 * a02;
    double M10 = a01 * D00 + C11 * a01 + a12 * a02;
    double M20 = a02 * D00 + a12 * a01 + C22 * a02;
    double M01 = C00 * a01 + a01 * D11 + a02 * a12;
    double M11 = a01 * a01 + C11 * D11 + a12 * a12;
    double M21 = a02 * a01 + a12 * D11 + C22 * a12;
    double M02 = C00 * a02 + a01 * a12 + a02 * D22;
    double M12 = a01 * a02 + C11 * a12 + a12 * D22;
    double M22 = a02 * a02 + a12 * a12 + C22 * D22;
    double n0 = M00 * M00 + M10 * M10 + M20 * M20;
    double n1 = M01 * M01 + M11 * M11 + M21 * M21;
    double n2 = M02 * M02 + M12 * M12 + M22 * M22;
    double vx, vy, vz, nn;
    if (n0 >= n1 && n0 >= n2) { vx = M00; vy = M10; vz = M20; nn = n0; }
    else if (n1 >= n2)        { vx = M01; vy = M11; vz = M21; nn = n1; }
    else                      { vx = M02; vy = M12; vz = M22; nn = n2; }
    if (nn > 1e-300) {
        double rn = 1.0 / sqrt(nn);
        vx *= rn; vy *= rn; vz *= rn;
    } else {
        vx = vy = vz = 0.0;
    }

    bool small = cntf < 2.0f;
    float bscale = small ? 0.0f : (float)(1.0 / denom);

    float* o = out + c * 16;
    o[0]  = (float)cx;
    o[1]  = (float)cy;
    o[2]  = (float)cz;
    o[3]  = (float)a00 * bscale;
    o[4]  = (float)a01 * bscale;
    o[5]  = (float)a02 * bscale;
    o[6]  = (float)a01 * bscale;
    o[7]  = (float)a11 * bscale;
    o[8]  = (float)a12 * bscale;
    o[9]  = (float)a02 * bscale;
    o[10] = (float)a12 * bscale;
    o[11] = (float)a22 * bscale;
    o[15] = cntf;

    pc[c] = make_float4((float)cx, (float)cy, (float)cz, (float)dirwt);
    pv[c] = make_float4((float)vx, (float)vy, (float)vz, cntf);
}

// ---------------- k_sc: block-per-cluster sc reduction + finalize v0 ------------
// Overflow list folded in: each block filters ov[] for its cluster (novf==0 in
// the common case -> one scalar load, loop skipped).
__global__ __launch_bounds__(256) void k_sc(const float4* __restrict__ P,
                                            const int* __restrict__ cnt,
                                            const float4* __restrict__ ov,
                                            const int* __restrict__ novf,
                                            const float4* __restrict__ pc,
                                            const float4* __restrict__ pv,
                                            float* __restrict__ out,
                                            int NSH, int CAP) {
    __shared__ float red[4];
    int c = blockIdx.x;
    int tid = threadIdx.x;
    float4 c4 = pc[c];
    float4 v4 = pv[c];
    float acc = 0.0f;
    for (int s = 0; s < NSH; s++) {
        int sub = c * NSH + s;
        int m = min(cnt[sub], CAP);
        size_t base = (size_t)sub * CAP;
        for (int i = tid; i < m; i += 256) {
            float4 d = P[base + i];
            float xc = d.x - c4.x;
            float yc = d.y - c4.y;
            float zc = d.z - c4.z;
            float x0 = xc * v4.x + yc * v4.y + zc * v4.z;
            float px = xc - x0 * v4.x;
            float py = yc - x0 * v4.y;
            float pz = zc - x0 * v4.z;
            acc += x0 * sqrtf(px * px + py * py + pz * pz);
        }
    }
    int movf = min(*novf, OVCAP);
    for (int i = tid; i < movf; i += 256) {
        float4 d = ov[i];
        if (__float_as_int(d.w) == c) {
            float xc = d.x - c4.x;
            float yc = d.y - c4.y;
            float zc = d.z - c4.z;
            float x0 = xc * v4.x + yc * v4.y + zc * v4.z;
            float px = xc - x0 * v4.x;
            float py = yc - x0 * v4.y;
            float pz = zc - x0 * v4.z;
            acc += x0 * sqrtf(px * px + py * py + pz * pz);
        }
    }
    int wid = tid >> 6, lane = tid & 63;
    for (int off = 32; off > 0; off >>= 1) acc += __shfl_down(acc, off);
    if (lane == 0) red[wid] = acc;
    __syncthreads();
    if (tid == 0) {
        float tot = red[0] + red[1] + red[2] + red[3];
        float s = (tot < 0.0f) ? -c4.w : c4.w;
        if (v4.w < 2.0f) s = 0.0f;
        out[c * 16 + 12] = v4.x * s;
        out[c * 16 + 13] = v4.y * s;
        out[c * 16 + 14] = v4.z * s;
    }
}

// ============================ FALLBACK (r1 structure) ============================
__global__ __launch_bounds__(1024) void k_accum_raw(const float* __restrict__ data,
                                                    const int* __restrict__ ids,
                                                    float* __restrict__ gmom, int n) {
    extern __shared__ float s[];
    for (int i = threadIdx.x; i < 10 * NC; i += blockDim.x) s[i] = 0.0f;
    __syncthreads();
    int stride = gridDim.x * blockDim.x;
    for (int i = blockIdx.x * blockDim.x + threadIdx.x; i < n; i += stride) {
        int id = ids[i];
        float x = data[i * 5 + 0], y = data[i * 5 + 1], z = data[i * 5 + 2];
        atomicAdd(&s[0 * NC + id], 1.0f);
        atomicAdd(&s[1 * NC + id], x);
        atomicAdd(&s[2 * NC + id], y);
        atomicAdd(&s[3 * NC + id], z);
        atomicAdd(&s[4 * NC + id], x * x);
        atomicAdd(&s[5 * NC + id], x * y);
        atomicAdd(&s[6 * NC + id], x * z);
        atomicAdd(&s[7 * NC + id], y * y);
        atomicAdd(&s[8 * NC + id], y * z);
        atomicAdd(&s[9 * NC + id], z * z);
    }
    __syncthreads();
    for (int i = threadIdx.x; i < 10 * NC; i += blockDim.x) {
        float v = s[i];
        if (v != 0.0f) atomicAdd(&gmom[i], v);
    }
}

__global__ void k_eigen_fb(const float* __restrict__ gmom, float* __restrict__ out,
                           float4* __restrict__ pc, float4* __restrict__ pv) {
    int c = blockIdx.x * blockDim.x + threadIdx.x;
    if (c >= NC) return;
    float cnt = gmom[0 * NC + c];
    float sx  = gmom[1 * NC + c], sy  = gmom[2 * NC + c], sz  = gmom[3 * NC + c];
    float sxx = gmom[4 * NC + c], sxy = gmom[5 * NC + c], sxz = gmom[6 * NC + c];
    float syy = gmom[7 * NC + c], syz = gmom[8 * NC + c], szz = gmom[9 * NC + c];
    double dn  = (double)cnt;
    double inv = 1.0 / fmax(dn, 1.0);
    double cx = sx * inv, cy = sy * inv, cz = sz * inv;
    double a00 = (double)sxx - dn * cx * cx;
    double a01 = (double)sxy - dn * cx * cy;
    double a02 = (double)sxz - dn * cx * cz;
    double a11 = (double)syy - dn * cy * cy;
    double a12 = (double)syz - dn * cy * cz;
    double a22 = (double)szz - dn * cz * cz;
    double q  = (a00 + a11 + a22) / 3.0;
    double p1 = a01 * a01 + a02 * a02 + a12 * a12;
    double b00 = a00 - q, b11 = a11 - q, b22 = a22 - q;
    double p2 = b00 * b00 + b11 * b11 + b22 * b22 + 2.0 * p1;
    double w0, w1, w2;
    if (!(p2 > 0.0)) { w0 = w1 = w2 = q; }
    else {
        double p  = sqrt(p2 / 6.0);
        double ip = 1.0 / p;
        double c00 = b00 * ip, c01 = a01 * ip, c02 = a02 * ip;
        double c11 = b11 * ip, c12 = a12 * ip, c22 = b22 * ip;
        double detB = c00 * (c11 * c22 - c12 * c12)
                    - c01 * (c01 * c22 - c12 * c02)
                    + c02 * (c01 * c12 - c11 * c02);
        double r = fmin(1.0, fmax(-1.0, detB * 0.5));
        double phi = acos(r) / 3.0;
        w2 = q + 2.0 * p * cos(phi);
        w0 = q + 2.0 * p * cos(phi + 2.0943951023931953);
        w1 = 3.0 * q - w2 - w0;
    }
    double denom = (w2 == 0.0) ? 1.0 : w2;
    double dirwt = (w2 == 0.0) ? 0.0 : (1.0 - w1 / w2);
    double C00 = a00 - w1, C11 = a11 - w1, C22 = a22 - w1;
    double D00 = a00 - w0, D11 = a11 - w0, D22 = a22 - w0;
    double M00 = C00 * D00 + a01 * a01 + a02 * a02;
    double M10 = a01 * D00 + C11 * a01 + a12 * a02;
    double M20 = a02 * D00 + a12 * a01 + C22 * a02;
    double M01 = C00 * a01 + a01 * D11 + a02 * a12;
    double M11 = a01 * a01 + C11 * D11 + a12 * a12;
    double M21 = a02 * a01 + a12 * D11 + C22 * a12;
    double M02 = C00 * a02 + a01 * a12 + a02 * D22;
    double M12 = a01 * a02 + C11 * a12 + a12 * D22;
    double M22 = a02 * a02 + a12 * a12 + C22 * D22;
    double n0 = M00 * M00 + M10 * M10 + M20 * M20;
    double n1 = M01 * M01 + M11 * M11 + M21 * M21;
    double n2 = M02 * M02 + M12 * M12 + M22 * M22;
    double vx, vy, vz, nn;
    if (n0 >= n1 && n0 >= n2) { vx = M00; vy = M10; vz = M20; nn = n0; }
    else if (n1 >= n2)        { vx = M01; vy = M11; vz = M21; nn = n1; }
    else                      { vx = M02; vy = M12; vz = M22; nn = n2; }
    if (nn > 1e-300) { double rn = 1.0 / sqrt(nn); vx *= rn; vy *= rn; vz *= rn; }
    else { vx = vy = vz = 0.0; }
    bool small = cnt < 2.0f;
    float bscale = small ? 0.0f : (float)(1.0 / denom);
    float* o = out + c * 16;
    o[0] = (float)cx; o[1] = (float)cy; o[2] = (float)cz;
    o[3] = (float)a00 * bscale; o[4] = (float)a01 * bscale; o[5] = (float)a02 * bscale;
    o[6] = (float)a01 * bscale; o[7] = (float)a11 * bscale; o[8] = (float)a12 * bscale;
    o[9] = (float)a02 * bscale; o[10] = (float)a12 * bscale; o[11] = (float)a22 * bscale;
    o[15] = cnt;
    pc[c] = make_float4((float)cx, (float)cy, (float)cz, (float)dirwt);
    pv[c] = make_float4((float)vx, (float)vy, (float)vz, cnt);
}

__global__ __launch_bounds__(1024) void k_sc_raw(const float* __restrict__ data,
                                                 const int* __restrict__ ids,
                                                 const float4* __restrict__ pc,
                                                 const float4* __restrict__ pv,
                                                 float* __restrict__ gsc, int n) {
    extern __shared__ float4 sl4[];
    float4* spc = sl4;
    float4* spv = sl4 + NC;
    float*  ssc = (float*)(sl4 + 2 * NC);
    for (int i = threadIdx.x; i < NC; i += blockDim.x) {
        spc[i] = pc[i]; spv[i] = pv[i]; ssc[i] = 0.0f;
    }
    __syncthreads();
    int stride = gridDim.x * blockDim.x;
    for (int i = blockIdx.x * blockDim.x + threadIdx.x; i < n; i += stride) {
        int id = ids[i];
        float4 c4 = spc[id];
        float4 v4 = spv[id];
        float xc = data[i * 5 + 0] - c4.x;
        float yc = data[i * 5 + 1] - c4.y;
        float zc = data[i * 5 + 2] - c4.z;
        float x0 = xc * v4.x + yc * v4.y + zc * v4.z;
        float px = xc - x0 * v4.x;
        float py = yc - x0 * v4.y;
        float pz = zc - x0 * v4.z;
        atomicAdd(&ssc[id], x0 * sqrtf(px * px + py * py + pz * pz));
    }
    __syncthreads();
    for (int i = threadIdx.x; i < NC; i += blockDim.x) {
        float v = ssc[i];
        if (v != 0.0f) atomicAdd(&gsc[i], v);
    }
}

__global__ void k_final_fb(const float4* __restrict__ pc, const float4* __restrict__ pv,
                           const float* __restrict__ gsc, float* __restrict__ out) {
    int c = blockIdx.x * blockDim.x + threadIdx.x;
    if (c >= NC) return;
    float4 c4 = pc[c];
    float4 v4 = pv[c];
    float s = (gsc[c] < 0.0f) ? -c4.w : c4.w;
    if (v4.w < 2.0f) s = 0.0f;
    out[c * 16 + 12] = v4.x * s;
    out[c * 16 + 13] = v4.y * s;
    out[c * 16 + 14] = v4.z * s;
}

// =================================================================================
extern "C" void kernel_launch(void* const* d_in, const int* in_sizes, int n_in,
                              void* d_out, int out_size, void* d_ws, size_t ws_size,
                              hipStream_t stream) {
    const float* data = (const float*)d_in[0];
    const int*   ids  = (const int*)d_in[1];
    float* out = (float*)d_out;
    int n = in_sizes[1];

    char* ws = (char*)d_ws;
    // layout (bytes):
    //   gmom : 40960 f    @ 0        (163840)
    //   gsc  : 4096 f     @ 163840   (16384)   [fallback only]
    //   cnt  : 32768 i    @ 180224   (131072)
    //   novf : 1 i        @ 311296   (pad -> 311552)
    //   pc   : 4096 f4    @ 311552   (65536)
    //   pv   : 4096 f4    @ 377088   (65536)
    //   ov   : 131072 f4  @ 442624   (2097152)
    //   P    : float4     @ 2539776  (NC*NSH*CAP*16)
    float*  gmom = (float*)(ws);
    float*  gsc  = (float*)(ws + 163840);
    int*    cnt  = (int*)(ws + 180224);
    int*    novf = (int*)(ws + 311296);
    float4* pc   = (float4*)(ws + 311552);
    float4* pv   = (float4*)(ws + 377088);
    float4* ov   = (float4*)(ws + 442624);
    float4* P    = (float4*)(ws + 2539776);
    const size_t base = 2539776;

    // CAP % 4 == 0 keeps sub-bins 64B-line-aligned (4 float4 per line).
    int NSH = 0, CAP = 0;
    if      (ws_size >= base + (size_t)NC * 8 * 184 * 16)  { NSH = 8; CAP = 184; }
    else if (ws_size >= base + (size_t)NC * 4 * 300 * 16)  { NSH = 4; CAP = 300; }
    else if (ws_size >= base + (size_t)NC * 2 * 552 * 16)  { NSH = 2; CAP = 552; }
    else if (ws_size >= base + (size_t)NC * 1 * 1024 * 16) { NSH = 1; CAP = 1024; }
    else if (ws_size >= base + (size_t)NC * 1 * 936 * 16)  { NSH = 1; CAP = 936; }

    if (NSH > 0) {
        hipMemsetAsync(ws, 0, 311552, stream);  // gmom + gsc + cnt + novf
        hipLaunchKernelGGL(k_scatter, dim3(4096), dim3(256), 0, stream,
                           data, ids, P, cnt, ov, novf, gmom, n, NSH, CAP);
        hipLaunchKernelGGL(k_reduce, dim3(NC), dim3(256), 0, stream,
                           P, cnt, gmom, out, pc, pv, NSH, CAP);
        hipLaunchKernelGGL(k_sc, dim3(NC), dim3(256), 0, stream,
                           P, cnt, ov, novf, pc, pv, out, NSH, CAP);
    } else {
        hipMemsetAsync(ws, 0, 180224, stream);
        hipLaunchKernelGGL(k_accum_raw, dim3(256), dim3(1024), 10 * NC * 4, stream,
                           data, ids, gmom, n);
        hipLaunchKernelGGL(k_eigen_fb, dim3(16), dim3(256), 0, stream, gmom, out, pc, pv);
        hipLaunchKernelGGL(k_sc_raw, dim3(256), dim3(1024), 2 * NC * 16 + NC * 4, stream,
                           data, ids, pc, pv, gsc, n);
        hipLaunchKernelGGL(k_final_fb, dim3(16), dim3(256), 0, stream, pc, pv, gsc, out);
    }
}

// Round 6
// 285.246 us; speedup vs baseline: 1.0807x; 1.0807x over previous
//
#include <hip/hip_runtime.h>
#include <math.h>

#define NC 4096
#define OVCAP 131072

// Real XCD id: s_getreg(HW_REG_XCC_ID=20, offset 0, size 4) [measured m09: 0..7]
__device__ __forceinline__ int xcd_id() {
    return (int)__builtin_amdgcn_s_getreg(20 | (0 << 6) | ((4 - 1) << 11));
}

// ============================ FAST PATH ==========================================
// k_scatter: bin voxels into per-(XCD-shard, cluster) contiguous float4 bins.
// shard = REAL XCC_ID -> all 4 float4 fills of each 64B line come from the same
// XCD's L2 -> one full-line writeback (kills the 3.2x cross-XCD write amp).
// k_reduce: block-per-cluster atomic-free moment reduction + inline eigensolve.
// k_sc:     block-per-cluster sc reduction (+ overflow list) + v0 finalize.

__global__ __launch_bounds__(256) void k_scatter(const float* __restrict__ data,
                                                 const int* __restrict__ ids,
                                                 float4* __restrict__ P,
                                                 int* __restrict__ cnt,
                                                 float4* __restrict__ ov,
                                                 int* __restrict__ novf,
                                                 float* __restrict__ gmom,
                                                 int n, int NSH, int CAP) {
    __shared__ float st[256 * 5];
    int shard = xcd_id() & (NSH - 1);     // XCD-private bins (NSH=8: exact)
    int ntiles = (n + 255) / 256;
    for (int t = blockIdx.x; t < ntiles; t += gridDim.x) {
        int vbase = t * 256;
        int fbase = vbase * 5;
        int nf = min(256 * 5, n * 5 - fbase);
        for (int j = threadIdx.x; j < nf; j += 256)
            st[j] = data[fbase + j];
        __syncthreads();
        int v = vbase + threadIdx.x;
        if (v < n) {
            int l = threadIdx.x * 5;
            float x = st[l], y = st[l + 1], z = st[l + 2];
            int id = ids[v];
            int sub = shard * NC + id;    // shard-major: lines are XCD-private
            int pos = atomicAdd(&cnt[sub], 1);
            if (pos < CAP) {
                P[(size_t)sub * CAP + pos] = make_float4(x, y, z, 0.0f);
            } else {
                // rare overflow: moments exactly via global atomics; sc via list
                int ovi = atomicAdd(novf, 1);
                if (ovi < OVCAP) ov[ovi] = make_float4(x, y, z, __int_as_float(id));
                atomicAdd(&gmom[0 * NC + id], 1.0f);
                atomicAdd(&gmom[1 * NC + id], x);
                atomicAdd(&gmom[2 * NC + id], y);
                atomicAdd(&gmom[3 * NC + id], z);
                atomicAdd(&gmom[4 * NC + id], x * x);
                atomicAdd(&gmom[5 * NC + id], x * y);
                atomicAdd(&gmom[6 * NC + id], x * z);
                atomicAdd(&gmom[7 * NC + id], y * y);
                atomicAdd(&gmom[8 * NC + id], y * z);
                atomicAdd(&gmom[9 * NC + id], z * z);
            }
        }
        __syncthreads();
    }
}

// ---------------- k_reduce: moments + eigensolve + B/center/count ---------------
// pc[c] = {cx, cy, cz, dirwt}; pv[c] = {vx, vy, vz, cnt}
__global__ __launch_bounds__(256) void k_reduce(const float4* __restrict__ P,
                                                const int* __restrict__ cnt,
                                                const float* __restrict__ gmom,
                                                float* __restrict__ out,
                                                float4* __restrict__ pc,
                                                float4* __restrict__ pv,
                                                int NSH, int CAP) {
    __shared__ float red[4 * 10];
    __shared__ float mom[10];
    int c = blockIdx.x;
    int tid = threadIdx.x;
    float a0 = 0, a1 = 0, a2 = 0, a3 = 0, a4 = 0, a5 = 0, a6 = 0, a7 = 0, a8 = 0, a9 = 0;
    for (int s = 0; s < NSH; s++) {
        int sub = s * NC + c;
        int m = min(cnt[sub], CAP);
        size_t base = (size_t)sub * CAP;
        for (int i = tid; i < m; i += 256) {
            float4 d = P[base + i];
            float x = d.x, y = d.y, z = d.z;
            a0 += 1.0f;
            a1 += x; a2 += y; a3 += z;
            a4 += x * x; a5 += x * y; a6 += x * z;
            a7 += y * y; a8 += y * z; a9 += z * z;
        }
    }
    float acc[10] = {a0, a1, a2, a3, a4, a5, a6, a7, a8, a9};
    int wid = tid >> 6, lane = tid & 63;
#pragma unroll
    for (int k = 0; k < 10; k++) {
        float v = acc[k];
        for (int off = 32; off > 0; off >>= 1) v += __shfl_down(v, off);
        if (lane == 0) red[wid * 10 + k] = v;
    }
    __syncthreads();
    if (tid < 10) {
        // overflow contributions were pre-added into gmom by k_scatter
        mom[tid] = red[0 + tid] + red[10 + tid] + red[20 + tid] + red[30 + tid]
                 + gmom[tid * NC + c];
    }
    __syncthreads();
    if (tid != 0) return;

    float cntf = mom[0];
    double dn  = (double)cntf;
    double inv = 1.0 / fmax(dn, 1.0);
    double cx = mom[1] * inv, cy = mom[2] * inv, cz = mom[3] * inv;

    double a00 = (double)mom[4] - dn * cx * cx;
    double a01 = (double)mom[5] - dn * cx * cy;
    double a02 = (double)mom[6] - dn * cx * cz;
    double a11 = (double)mom[7] - dn * cy * cy;
    double a12 = (double)mom[8] - dn * cy * cz;
    double a22 = (double)mom[9] - dn * cz * cz;

    // Smith's trigonometric eigenvalues
    double q  = (a00 + a11 + a22) / 3.0;
    double p1 = a01 * a01 + a02 * a02 + a12 * a12;
    double b00 = a00 - q, b11 = a11 - q, b22 = a22 - q;
    double p2 = b00 * b00 + b11 * b11 + b22 * b22 + 2.0 * p1;
    double w0, w1, w2;
    if (!(p2 > 0.0)) {
        w0 = w1 = w2 = q;
    } else {
        double p  = sqrt(p2 / 6.0);
        double ip = 1.0 / p;
        double c00 = b00 * ip, c01 = a01 * ip, c02 = a02 * ip;
        double c11 = b11 * ip, c12 = a12 * ip, c22 = b22 * ip;
        double detB = c00 * (c11 * c22 - c12 * c12)
                    - c01 * (c01 * c22 - c12 * c02)
                    + c02 * (c01 * c12 - c11 * c02);
        double r = fmin(1.0, fmax(-1.0, detB * 0.5));
        double phi = acos(r) / 3.0;
        w2 = q + 2.0 * p * cos(phi);
        w0 = q + 2.0 * p * cos(phi + 2.0943951023931953);
        w1 = 3.0 * q - w2 - w0;
    }

    double denom = (w2 == 0.0) ? 1.0 : w2;
    double dirwt = (w2 == 0.0) ? 0.0 : (1.0 - w1 / w2);

    // eigenvector of w2 via (A - w1 I)(A - w0 I)
    double C00 = a00 - w1, C11 = a11 - w1, C22 = a22 - w1;
    double D00 = a00 - w0, D11 = a11 - w0, D22 = a22 - w0;
    double M00 = C00 * D00 + a01 * a01 + a02 * a02;
    double M10 = a01 * D00 + C11 * a01 + a12 * a02;
    double M20 = a02 * D00 + a12 * a01 + C22 * a02;
    double M01 = C00 * a01 + a01 * D11 + a02 * a12;
    double M11 = a01 * a01 + C11 * D11 + a12 * a12;
    double M21 = a02 * a01 + a12 * D11 + C22 * a12;
    double M02 = C00 * a02 + a01 * a12 + a02 * D22;
    double M12 = a01 * a02 + C11 * a12 + a12 * D22;
    double M22 = a02 * a02 + a12 * a12 + C22 * D22;
    double n0 = M00 * M00 + M10 * M10 + M20 * M20;
    double n1 = M01 * M01 + M11 * M11 + M21 * M21;
    double n2 = M02 * M02 + M12 * M12 + M22 * M22;
    double vx, vy, vz, nn;
    if (n0 >= n1 && n0 >= n2) { vx = M00; vy = M10; vz = M20; nn = n0; }
    else if (n1 >= n2)        { vx = M01; vy = M11; vz = M21; nn = n1; }
    else                      { vx = M02; vy = M12; vz = M22; nn = n2; }
    if (nn > 1e-300) {
        double rn = 1.0 / sqrt(nn);
        vx *= rn; vy *= rn; vz *= rn;
    } else {
        vx = vy = vz = 0.0;
    }

    bool small = cntf < 2.0f;
    float bscale = small ? 0.0f : (float)(1.0 / denom);

    float* o = out + c * 16;
    o[0]  = (float)cx;
    o[1]  = (float)cy;
    o[2]  = (float)cz;
    o[3]  = (float)a00 * bscale;
    o[4]  = (float)a01 * bscale;
    o[5]  = (float)a02 * bscale;
    o[6]  = (float)a01 * bscale;
    o[7]  = (float)a11 * bscale;
    o[8]  = (float)a12 * bscale;
    o[9]  = (float)a02 * bscale;
    o[10] = (float)a12 * bscale;
    o[11] = (float)a22 * bscale;
    o[15] = cntf;

    pc[c] = make_float4((float)cx, (float)cy, (float)cz, (float)dirwt);
    pv[c] = make_float4((float)vx, (float)vy, (float)vz, cntf);
}

// ---------------- k_sc: block-per-cluster sc reduction + finalize v0 ------------
__global__ __launch_bounds__(256) void k_sc(const float4* __restrict__ P,
                                            const int* __restrict__ cnt,
                                            const float4* __restrict__ ov,
                                            const int* __restrict__ novf,
                                            const float4* __restrict__ pc,
                                            const float4* __restrict__ pv,
                                            float* __restrict__ out,
                                            int NSH, int CAP) {
    __shared__ float red[4];
    int c = blockIdx.x;
    int tid = threadIdx.x;
    float4 c4 = pc[c];
    float4 v4 = pv[c];
    float acc = 0.0f;
    for (int s = 0; s < NSH; s++) {
        int sub = s * NC + c;
        int m = min(cnt[sub], CAP);
        size_t base = (size_t)sub * CAP;
        for (int i = tid; i < m; i += 256) {
            float4 d = P[base + i];
            float xc = d.x - c4.x;
            float yc = d.y - c4.y;
            float zc = d.z - c4.z;
            float x0 = xc * v4.x + yc * v4.y + zc * v4.z;
            float px = xc - x0 * v4.x;
            float py = yc - x0 * v4.y;
            float pz = zc - x0 * v4.z;
            acc += x0 * sqrtf(px * px + py * py + pz * pz);
        }
    }
    int movf = min(*novf, OVCAP);
    for (int i = tid; i < movf; i += 256) {
        float4 d = ov[i];
        if (__float_as_int(d.w) == c) {
            float xc = d.x - c4.x;
            float yc = d.y - c4.y;
            float zc = d.z - c4.z;
            float x0 = xc * v4.x + yc * v4.y + zc * v4.z;
            float px = xc - x0 * v4.x;
            float py = yc - x0 * v4.y;
            float pz = zc - x0 * v4.z;
            acc += x0 * sqrtf(px * px + py * py + pz * pz);
        }
    }
    int wid = tid >> 6, lane = tid & 63;
    for (int off = 32; off > 0; off >>= 1) acc += __shfl_down(acc, off);
    if (lane == 0) red[wid] = acc;
    __syncthreads();
    if (tid == 0) {
        float tot = red[0] + red[1] + red[2] + red[3];
        float s = (tot < 0.0f) ? -c4.w : c4.w;
        if (v4.w < 2.0f) s = 0.0f;
        out[c * 16 + 12] = v4.x * s;
        out[c * 16 + 13] = v4.y * s;
        out[c * 16 + 14] = v4.z * s;
    }
}

// ============================ FALLBACK (r1 structure) ============================
__global__ __launch_bounds__(1024) void k_accum_raw(const float* __restrict__ data,
                                                    const int* __restrict__ ids,
                                                    float* __restrict__ gmom, int n) {
    extern __shared__ float s[];
    for (int i = threadIdx.x; i < 10 * NC; i += blockDim.x) s[i] = 0.0f;
    __syncthreads();
    int stride = gridDim.x * blockDim.x;
    for (int i = blockIdx.x * blockDim.x + threadIdx.x; i < n; i += stride) {
        int id = ids[i];
        float x = data[i * 5 + 0], y = data[i * 5 + 1], z = data[i * 5 + 2];
        atomicAdd(&s[0 * NC + id], 1.0f);
        atomicAdd(&s[1 * NC + id], x);
        atomicAdd(&s[2 * NC + id], y);
        atomicAdd(&s[3 * NC + id], z);
        atomicAdd(&s[4 * NC + id], x * x);
        atomicAdd(&s[5 * NC + id], x * y);
        atomicAdd(&s[6 * NC + id], x * z);
        atomicAdd(&s[7 * NC + id], y * y);
        atomicAdd(&s[8 * NC + id], y * z);
        atomicAdd(&s[9 * NC + id], z * z);
    }
    __syncthreads();
    for (int i = threadIdx.x; i < 10 * NC; i += blockDim.x) {
        float v = s[i];
        if (v != 0.0f) atomicAdd(&gmom[i], v);
    }
}

__global__ void k_eigen_fb(const float* __restrict__ gmom, float* __restrict__ out,
                           float4* __restrict__ pc, float4* __restrict__ pv) {
    int c = blockIdx.x * blockDim.x + threadIdx.x;
    if (c >= NC) return;
    float cnt = gmom[0 * NC + c];
    float sx  = gmom[1 * NC + c], sy  = gmom[2 * NC + c], sz  = gmom[3 * NC + c];
    float sxx = gmom[4 * NC + c], sxy = gmom[5 * NC + c], sxz = gmom[6 * NC + c];
    float syy = gmom[7 * NC + c], syz = gmom[8 * NC + c], szz = gmom[9 * NC + c];
    double dn  = (double)cnt;
    double inv = 1.0 / fmax(dn, 1.0);
    double cx = sx * inv, cy = sy * inv, cz = sz * inv;
    double a00 = (double)sxx - dn * cx * cx;
    double a01 = (double)sxy - dn * cx * cy;
    double a02 = (double)sxz - dn * cx * cz;
    double a11 = (double)syy - dn * cy * cy;
    double a12 = (double)syz - dn * cy * cz;
    double a22 = (double)szz - dn * cz * cz;
    double q  = (a00 + a11 + a22) / 3.0;
    double p1 = a01 * a01 + a02 * a02 + a12 * a12;
    double b00 = a00 - q, b11 = a11 - q, b22 = a22 - q;
    double p2 = b00 * b00 + b11 * b11 + b22 * b22 + 2.0 * p1;
    double w0, w1, w2;
    if (!(p2 > 0.0)) { w0 = w1 = w2 = q; }
    else {
        double p  = sqrt(p2 / 6.0);
        double ip = 1.0 / p;
        double c00 = b00 * ip, c01 = a01 * ip, c02 = a02 * ip;
        double c11 = b11 * ip, c12 = a12 * ip, c22 = b22 * ip;
        double detB = c00 * (c11 * c22 - c12 * c12)
                    - c01 * (c01 * c22 - c12 * c02)
                    + c02 * (c01 * c12 - c11 * c02);
        double r = fmin(1.0, fmax(-1.0, detB * 0.5));
        double phi = acos(r) / 3.0;
        w2 = q + 2.0 * p * cos(phi);
        w0 = q + 2.0 * p * cos(phi + 2.0943951023931953);
        w1 = 3.0 * q - w2 - w0;
    }
    double denom = (w2 == 0.0) ? 1.0 : w2;
    double dirwt = (w2 == 0.0) ? 0.0 : (1.0 - w1 / w2);
    double C00 = a00 - w1, C11 = a11 - w1, C22 = a22 - w1;
    double D00 = a00 - w0, D11 = a11 - w0, D22 = a22 - w0;
    double M00 = C00 * D00 + a01 * a01 + a02 * a02;
    double M10 = a01 * D00 + C11 * a01 + a12 * a02;
    double M20 = a02 * D00 + a12 * a01 + C22 * a02;
    double M01 = C00 * a01 + a01 * D11 + a02 * a12;
    double M11 = a01 * a01 + C11 * D11 + a12 * a12;
    double M21 = a02 * a01 + a12 * D11 + C22 * a12;
    double M02 = C00 * a02 + a01 * a12 + a02 * D22;
    double M12 = a01 * a02 + C11 * a12 + a12 * D22;
    double M22 = a02 * a02 + a12 * a12 + C22 * D22;
    double n0 = M00 * M00 + M10 * M10 + M20 * M20;
    double n1 = M01 * M01 + M11 * M11 + M21 * M21;
    double n2 = M02 * M02 + M12 * M12 + M22 * M22;
    double vx, vy, vz, nn;
    if (n0 >= n1 && n0 >= n2) { vx = M00; vy = M10; vz = M20; nn = n0; }
    else if (n1 >= n2)        { vx = M01; vy = M11; vz = M21; nn = n1; }
    else                      { vx = M02; vy = M12; vz = M22; nn = n2; }
    if (nn > 1e-300) { double rn = 1.0 / sqrt(nn); vx *= rn; vy *= rn; vz *= rn; }
    else { vx = vy = vz = 0.0; }
    bool small = cnt < 2.0f;
    float bscale = small ? 0.0f : (float)(1.0 / denom);
    float* o = out + c * 16;
    o[0] = (float)cx; o[1] = (float)cy; o[2] = (float)cz;
    o[3] = (float)a00 * bscale; o[4] = (float)a01 * bscale; o[5] = (float)a02 * bscale;
    o[6] = (float)a01 * bscale; o[7] = (float)a11 * bscale; o[8] = (float)a12 * bscale;
    o[9] = (float)a02 * bscale; o[10] = (float)a12 * bscale; o[11] = (float)a22 * bscale;
    o[15] = cnt;
    pc[c] = make_float4((float)cx, (float)cy, (float)cz, (float)dirwt);
    pv[c] = make_float4((float)vx, (float)vy, (float)vz, cnt);
}

__global__ __launch_bounds__(1024) void k_sc_raw(const float* __restrict__ data,
                                                 const int* __restrict__ ids,
                                                 const float4* __restrict__ pc,
                                                 const float4* __restrict__ pv,
                                                 float* __restrict__ gsc, int n) {
    extern __shared__ float4 sl4[];
    float4* spc = sl4;
    float4* spv = sl4 + NC;
    float*  ssc = (float*)(sl4 + 2 * NC);
    for (int i = threadIdx.x; i < NC; i += blockDim.x) {
        spc[i] = pc[i]; spv[i] = pv[i]; ssc[i] = 0.0f;
    }
    __syncthreads();
    int stride = gridDim.x * blockDim.x;
    for (int i = blockIdx.x * blockDim.x + threadIdx.x; i < n; i += stride) {
        int id = ids[i];
        float4 c4 = spc[id];
        float4 v4 = spv[id];
        float xc = data[i * 5 + 0] - c4.x;
        float yc = data[i * 5 + 1] - c4.y;
        float zc = data[i * 5 + 2] - c4.z;
        float x0 = xc * v4.x + yc * v4.y + zc * v4.z;
        float px = xc - x0 * v4.x;
        float py = yc - x0 * v4.y;
        float pz = zc - x0 * v4.z;
        atomicAdd(&ssc[id], x0 * sqrtf(px * px + py * py + pz * pz));
    }
    __syncthreads();
    for (int i = threadIdx.x; i < NC; i += blockDim.x) {
        float v = ssc[i];
        if (v != 0.0f) atomicAdd(&gsc[i], v);
    }
}

__global__ void k_final_fb(const float4* __restrict__ pc, const float4* __restrict__ pv,
                           const float* __restrict__ gsc, float* __restrict__ out) {
    int c = blockIdx.x * blockDim.x + threadIdx.x;
    if (c >= NC) return;
    float4 c4 = pc[c];
    float4 v4 = pv[c];
    float s = (gsc[c] < 0.0f) ? -c4.w : c4.w;
    if (v4.w < 2.0f) s = 0.0f;
    out[c * 16 + 12] = v4.x * s;
    out[c * 16 + 13] = v4.y * s;
    out[c * 16 + 14] = v4.z * s;
}

// =================================================================================
extern "C" void kernel_launch(void* const* d_in, const int* in_sizes, int n_in,
                              void* d_out, int out_size, void* d_ws, size_t ws_size,
                              hipStream_t stream) {
    const float* data = (const float*)d_in[0];
    const int*   ids  = (const int*)d_in[1];
    float* out = (float*)d_out;
    int n = in_sizes[1];

    char* ws = (char*)d_ws;
    // layout (bytes):
    //   gmom : 40960 f    @ 0        (163840)
    //   gsc  : 4096 f     @ 163840   (16384)   [fallback only]
    //   cnt  : 32768 i    @ 180224   (131072)
    //   novf : 1 i        @ 311296   (pad -> 311552)
    //   pc   : 4096 f4    @ 311552   (65536)
    //   pv   : 4096 f4    @ 377088   (65536)
    //   ov   : 131072 f4  @ 442624   (2097152)
    //   P    : float4     @ 2539776  (NC*NSH*CAP*16)
    float*  gmom = (float*)(ws);
    float*  gsc  = (float*)(ws + 163840);
    int*    cnt  = (int*)(ws + 180224);
    int*    novf = (int*)(ws + 311296);
    float4* pc   = (float4*)(ws + 311552);
    float4* pv   = (float4*)(ws + 377088);
    float4* ov   = (float4*)(ws + 442624);
    float4* P    = (float4*)(ws + 2539776);
    const size_t base = 2539776;

    // CAP % 4 == 0 keeps sub-bins 64B-line-aligned (4 float4 per line).
    int NSH = 0, CAP = 0;
    if      (ws_size >= base + (size_t)NC * 8 * 184 * 16)  { NSH = 8; CAP = 184; }
    else if (ws_size >= base + (size_t)NC * 4 * 300 * 16)  { NSH = 4; CAP = 300; }
    else if (ws_size >= base + (size_t)NC * 2 * 552 * 16)  { NSH = 2; CAP = 552; }
    else if (ws_size >= base + (size_t)NC * 1 * 1024 * 16) { NSH = 1; CAP = 1024; }
    else if (ws_size >= base + (size_t)NC * 1 * 936 * 16)  { NSH = 1; CAP = 936; }

    if (NSH > 0) {
        hipMemsetAsync(ws, 0, 311552, stream);  // gmom + gsc + cnt + novf
        hipLaunchKernelGGL(k_scatter, dim3(4096), dim3(256), 0, stream,
                           data, ids, P, cnt, ov, novf, gmom, n, NSH, CAP);
        hipLaunchKernelGGL(k_reduce, dim3(NC), dim3(256), 0, stream,
                           P, cnt, gmom, out, pc, pv, NSH, CAP);
        hipLaunchKernelGGL(k_sc, dim3(NC), dim3(256), 0, stream,
                           P, cnt, ov, novf, pc, pv, out, NSH, CAP);
    } else {
        hipMemsetAsync(ws, 0, 180224, stream);
        hipLaunchKernelGGL(k_accum_raw, dim3(256), dim3(1024), 10 * NC * 4, stream,
                           data, ids, gmom, n);
        hipLaunchKernelGGL(k_eigen_fb, dim3(16), dim3(256), 0, stream, gmom, out, pc, pv);
        hipLaunchKernelGGL(k_sc_raw, dim3(256), dim3(1024), 2 * NC * 16 + NC * 4, stream,
                           data, ids, pc, pv, gsc, n);
        hipLaunchKernelGGL(k_final_fb, dim3(16), dim3(256), 0, stream, pc, pv, gsc, out);
    }
}